// Round 1
// baseline (222.556 us; speedup 1.0000x reference)
//
#include <hip/hip_runtime.h>

// ---------------------------------------------------------------------------
// LocalWindowAttentionLayer on MI355X (gfx950)
// B=4 L=2048 D=512 H=8 DK=64 DF=2048 W=9
//
// Pipeline:
//  prep: transpose weights -> bf16 [N][K], concat qkv bias, x -> bf16
//  G1: QKV = xb @ WqkvT^T + bqkv          (8192 x 1536, K=512)  bf16 out
//  A : per (b,l): 9x9 scores/head, softmax, col-mean -> obar (8192 x 512) bf16
//  G2: newx = obar @ WoT^T + bo           (8192 x 512, K=512)   bf16 out
//  LN1: x1 = LN(x + newx)                 -> bf16
//  G3: h = gelu(x1 @ W1T^T + b1)          (8192 x 2048, K=512)  bf16 out
//  G4: y = h @ W2T^T + b2                 (8192 x 512, K=2048)  bf16 out
//  LN2: out = LN(x1 + y)                  -> fp32 d_out
// ---------------------------------------------------------------------------

typedef unsigned short u16;
typedef __attribute__((ext_vector_type(8))) short short8;   // 8 bf16 (4 VGPRs)
typedef __attribute__((ext_vector_type(4))) float floatx4;  // MFMA acc

#define DEV static __device__ __forceinline__

DEV float b2f(u16 u) {
  union { unsigned int i; float f; } x; x.i = ((unsigned int)u) << 16; return x.f;
}
DEV u16 f2b(float f) {  // round-to-nearest-even
  union { float f; unsigned int i; } x; x.f = f;
  unsigned int u = x.i + 0x7fffu + ((x.i >> 16) & 1u);
  return (u16)(u >> 16);
}

#define AS1 __attribute__((address_space(1)))
#define AS3 __attribute__((address_space(3)))
DEV void gload_lds16(const void* g, void* l) {
  __builtin_amdgcn_global_load_lds((const AS1 void*)g, (AS3 void*)l, 16, 0, 0);
}

// ---------------------------------------------------------------------------
// Tiled transpose: in (R x C) fp32 -> out (C x R) bf16
// ---------------------------------------------------------------------------
__global__ __launch_bounds__(256) void transpose_f2b(
    const float* __restrict__ in, u16* __restrict__ out, int R, int C) {
  __shared__ float tile[32][33];
  const int tx = threadIdx.x & 31, ty = threadIdx.x >> 5;
  const int bc = blockIdx.x * 32, br = blockIdx.y * 32;
  #pragma unroll
  for (int i = 0; i < 32; i += 8)
    tile[ty + i][tx] = in[(size_t)(br + ty + i) * C + bc + tx];
  __syncthreads();
  #pragma unroll
  for (int i = 0; i < 32; i += 8)
    out[(size_t)(bc + ty + i) * R + br + tx] = f2b(tile[tx][ty + i]);
}

__global__ __launch_bounds__(256) void concat_bias(
    const float* __restrict__ bq, const float* __restrict__ bk,
    const float* __restrict__ bv, float* __restrict__ o) {
  int i = blockIdx.x * 256 + threadIdx.x;
  if (i < 512) o[i] = bq[i];
  else if (i < 1024) o[i] = bk[i - 512];
  else if (i < 1536) o[i] = bv[i - 1024];
}

__global__ __launch_bounds__(256) void f2b_vec(
    const float* __restrict__ in, u16* __restrict__ out, int n4) {
  int i = blockIdx.x * 256 + threadIdx.x;
  if (i < n4) {
    float4 v = ((const float4*)in)[i];
    ushort4 o;
    o.x = f2b(v.x); o.y = f2b(v.y); o.z = f2b(v.z); o.w = f2b(v.w);
    ((ushort4*)out)[i] = o;
  }
}

// ---------------------------------------------------------------------------
// bf16 MFMA GEMM:  C[M][N] = A[M][K] @ BT[N][K]^T + bias ; EPI: 0=bias, 1=bias+gelu
// BM=BN=128, BK=32, 256 threads = 4 waves, each wave 64x64 (4x4 frags 16x16x32)
// ---------------------------------------------------------------------------
template<int EPI>
__global__ __launch_bounds__(256, 2) void gemm_bt(
    const u16* __restrict__ A, const u16* __restrict__ BT,
    const float* __restrict__ bias, u16* __restrict__ C,
    int M, int N, int K) {
  __shared__ __align__(16) u16 As[128 * 32];
  __shared__ __align__(16) u16 Bs[128 * 32];
  const int tid  = threadIdx.x;
  const int wave = tid >> 6, lane = tid & 63;
  const int l15 = lane & 15, l4 = lane >> 4;
  const int bm = blockIdx.y * 128, bn = blockIdx.x * 128;
  const int wm = (wave >> 1) * 64, wn = (wave & 1) * 64;

  floatx4 acc[4][4] = {};

  // staging: tile = 512 x 16B chunks; chunk ci -> row=ci>>2, kchunk=ci&3
  const int row0 = tid >> 2, kc0 = (tid & 3) * 8;
  const u16* gA = A  + (size_t)(bm + row0) * K + kc0;
  const u16* gB = BT + (size_t)(bn + row0) * K + kc0;
  u16* lA0 = As + wave * 512;        // (wave*64 chunks)*8 elems
  u16* lB0 = Bs + wave * 512;
  u16* lA1 = As + 2048 + wave * 512; // second half: chunks 256..511
  u16* lB1 = Bs + 2048 + wave * 512;

  for (int k0 = 0; k0 < K; k0 += 32) {
    gload_lds16(gA, lA0);
    gload_lds16(gB, lB0);
    gload_lds16(gA + (size_t)64 * K, lA1);
    gload_lds16(gB + (size_t)64 * K, lB1);
    gA += 32; gB += 32;
    __syncthreads();

    short8 af[4], bf[4];
    #pragma unroll
    for (int i = 0; i < 4; ++i) {
      af[i] = *(const short8*)(As + (wm + i * 16 + l15) * 32 + l4 * 8);
      bf[i] = *(const short8*)(Bs + (wn + i * 16 + l15) * 32 + l4 * 8);
    }
    #pragma unroll
    for (int i = 0; i < 4; ++i)
      #pragma unroll
      for (int j = 0; j < 4; ++j)
        acc[i][j] = __builtin_amdgcn_mfma_f32_16x16x32_bf16(af[i], bf[j], acc[i][j], 0, 0, 0);
    __syncthreads();
  }

  // epilogue: C row = bm+wm+i*16+(l4*4+r), col = bn+wn+j*16+l15
  float bv[4];
  #pragma unroll
  for (int j = 0; j < 4; ++j) bv[j] = bias[bn + wn + j * 16 + l15];
  #pragma unroll
  for (int i = 0; i < 4; ++i) {
    #pragma unroll
    for (int r = 0; r < 4; ++r) {
      size_t row = (size_t)(bm + wm + i * 16 + l4 * 4 + r);
      u16* cp = C + row * N + (bn + wn + l15);
      #pragma unroll
      for (int j = 0; j < 4; ++j) {
        float v = acc[i][j][r] + bv[j];
        if (EPI == 1) v = 0.5f * v * (1.0f + erff(v * 0.70710678118654752f));
        cp[j * 16] = f2b(v);
      }
    }
  }
}

// ---------------------------------------------------------------------------
// Attention: one block per (b,l). Stage 9 window rows of QKV (1536) in LDS,
// per-head 9x9 scores -> softmax -> column-mean -> obar (512) bf16.
// ---------------------------------------------------------------------------
__global__ __launch_bounds__(256) void attn_kernel(
    const u16* __restrict__ QKV, const float* __restrict__ bqkv,
    u16* __restrict__ obar) {
  __shared__ __align__(16) u16 S[9 * 1536];
  __shared__ float sc[8][9][9];
  __shared__ float wsm[8][9];
  const int tid = threadIdx.x;
  const int bl = blockIdx.x;
  const int b = bl >> 11, l = bl & 2047;

  // stage: 9 rows * 192 chunks(16B)
  for (int ci = tid; ci < 9 * 192; ci += 256) {
    int rowi = ci / 192, cc = ci % 192;
    int t = l + rowi - 4;
    short8 v;
    if ((unsigned)t < 2048u) {
      v = *(const short8*)(QKV + ((size_t)((b << 11) | t)) * 1536 + cc * 8);
    } else {
      #pragma unroll
      for (int j = 0; j < 8; ++j) v[j] = (short)f2b(bqkv[cc * 8 + j]);
    }
    *(short8*)(S + rowi * 1536 + cc * 8) = v;
  }
  __syncthreads();

  // scores: 8 heads * 81 (qw,kw) pairs, dot over 64
  for (int task = tid; task < 648; task += 256) {
    int h = task / 81, rem = task % 81;
    int qw = rem / 9, kw = rem % 9;
    const u16* qp = S + qw * 1536 + h * 64;
    const u16* kp = S + kw * 1536 + 512 + h * 64;
    float a = 0.f;
    #pragma unroll
    for (int d0 = 0; d0 < 64; d0 += 8) {
      short8 qv = *(const short8*)(qp + d0);
      short8 kv = *(const short8*)(kp + d0);
      #pragma unroll
      for (int j = 0; j < 8; ++j) a += b2f((u16)qv[j]) * b2f((u16)kv[j]);
    }
    sc[h][qw][kw] = a * 0.125f;
  }
  __syncthreads();

  // softmax rows (h,qw)
  if (tid < 72) {
    int h = tid / 9, qw = tid % 9;
    float m = sc[h][qw][0];
    #pragma unroll
    for (int kw = 1; kw < 9; ++kw) m = fmaxf(m, sc[h][qw][kw]);
    float e[9], s = 0.f;
    #pragma unroll
    for (int kw = 0; kw < 9; ++kw) { e[kw] = expf(sc[h][qw][kw] - m); s += e[kw]; }
    float inv = 1.f / s;
    #pragma unroll
    for (int kw = 0; kw < 9; ++kw) sc[h][qw][kw] = e[kw] * inv;
  }
  __syncthreads();

  // column mean over qw (x 1/9)
  if (tid < 72) {
    int h = tid / 9, kw = tid % 9;
    float s = 0.f;
    #pragma unroll
    for (int qw = 0; qw < 9; ++qw) s += sc[h][qw][kw];
    wsm[h][kw] = s * (1.f / 9.f);
  }
  __syncthreads();

  // obar[d] = sum_kw wsm[h][kw] * V[kw][d]
  for (int d = tid; d < 512; d += 256) {
    int h = d >> 6;
    float a = 0.f;
    #pragma unroll
    for (int kw = 0; kw < 9; ++kw) a += wsm[h][kw] * b2f(S[kw * 1536 + 1024 + d]);
    obar[(size_t)bl * 512 + d] = f2b(a);
  }
}

// ---------------------------------------------------------------------------
// LayerNorm over D=512. One wave per row, 4 rows per block.
// MODE 0: v = af(f32) + bb(bf16) -> outb bf16
// MODE 1: v = ab(bf16) + bb(bf16) -> outf fp32
// ---------------------------------------------------------------------------
template<int MODE>
__global__ __launch_bounds__(256) void ln_kernel(
    const float* __restrict__ af, const u16* __restrict__ ab,
    const u16* __restrict__ bb,
    const float* __restrict__ g, const float* __restrict__ be,
    u16* __restrict__ outb, float* __restrict__ outf) {
  const int wave = threadIdx.x >> 6, lane = threadIdx.x & 63;
  const size_t row = (size_t)blockIdx.x * 4 + wave;
  const size_t base = row * 512 + lane * 8;
  const int gi = lane * 8;
  float v[8];
  short8 b8 = *(const short8*)(bb + base);
  if (MODE == 0) {
    float4 a0 = *(const float4*)(af + base);
    float4 a1 = *(const float4*)(af + base + 4);
    v[0] = a0.x; v[1] = a0.y; v[2] = a0.z; v[3] = a0.w;
    v[4] = a1.x; v[5] = a1.y; v[6] = a1.z; v[7] = a1.w;
  } else {
    short8 a8 = *(const short8*)(ab + base);
    #pragma unroll
    for (int j = 0; j < 8; ++j) v[j] = b2f((u16)a8[j]);
  }
  #pragma unroll
  for (int j = 0; j < 8; ++j) v[j] += b2f((u16)b8[j]);

  float s = 0.f;
  #pragma unroll
  for (int j = 0; j < 8; ++j) s += v[j];
  #pragma unroll
  for (int off = 32; off >= 1; off >>= 1) s += __shfl_xor(s, off, 64);
  const float mean = s * (1.f / 512.f);
  float sq = 0.f;
  #pragma unroll
  for (int j = 0; j < 8; ++j) { float d = v[j] - mean; sq += d * d; }
  #pragma unroll
  for (int off = 32; off >= 1; off >>= 1) sq += __shfl_xor(sq, off, 64);
  const float rs = rsqrtf(sq * (1.f / 512.f) + 1e-5f);

  if (MODE == 0) {
    short8 o;
    #pragma unroll
    for (int j = 0; j < 8; ++j)
      o[j] = (short)f2b((v[j] - mean) * rs * g[gi + j] + be[gi + j]);
    *(short8*)(outb + base) = o;
  } else {
    float4 o0, o1;
    o0.x = (v[0] - mean) * rs * g[gi + 0] + be[gi + 0];
    o0.y = (v[1] - mean) * rs * g[gi + 1] + be[gi + 1];
    o0.z = (v[2] - mean) * rs * g[gi + 2] + be[gi + 2];
    o0.w = (v[3] - mean) * rs * g[gi + 3] + be[gi + 3];
    o1.x = (v[4] - mean) * rs * g[gi + 4] + be[gi + 4];
    o1.y = (v[5] - mean) * rs * g[gi + 5] + be[gi + 5];
    o1.z = (v[6] - mean) * rs * g[gi + 6] + be[gi + 6];
    o1.w = (v[7] - mean) * rs * g[gi + 7] + be[gi + 7];
    *(float4*)(outf + base) = o0;
    *(float4*)(outf + base + 4) = o1;
  }
}

// ---------------------------------------------------------------------------
extern "C" void kernel_launch(void* const* d_in, const int* in_sizes, int n_in,
                              void* d_out, int out_size, void* d_ws, size_t ws_size,
                              hipStream_t stream) {
  const float* x   = (const float*)d_in[0];
  const float* Wq  = (const float*)d_in[1];
  const float* bq  = (const float*)d_in[2];
  const float* Wk  = (const float*)d_in[3];
  const float* bk  = (const float*)d_in[4];
  const float* Wv  = (const float*)d_in[5];
  const float* bv  = (const float*)d_in[6];
  const float* Wo  = (const float*)d_in[7];
  const float* bo  = (const float*)d_in[8];
  const float* W1  = (const float*)d_in[9];
  const float* b1  = (const float*)d_in[10];
  const float* W2  = (const float*)d_in[11];
  const float* b2  = (const float*)d_in[12];
  const float* g1  = (const float*)d_in[13];
  const float* be1 = (const float*)d_in[14];
  const float* g2  = (const float*)d_in[15];
  const float* be2 = (const float*)d_in[16];

  char* w = (char*)d_ws;
  u16*   xb    = (u16*)  (w + 0);           //  8 MB
  u16*   WqkvT = (u16*)  (w + 8388608);     //  1536x512 bf16
  u16*   WoT   = (u16*)  (w + 9961472);     //  512x512
  u16*   W1T   = (u16*)  (w + 10485760);    //  2048x512
  u16*   W2T   = (u16*)  (w + 12582912);    //  512x2048
  float* bqkv  = (float*)(w + 14680064);    //  1536 f32
  u16*   QKV   = (u16*)  (w + 14686208);    //  8192x1536 bf16 (dead after attn)
  u16*   obar  = (u16*)  (w + 39852032);    //  8192x512  bf16 (dead after G2)
  u16*   hbuf  = QKV;                       //  8192x2048 bf16 (aliases QKV+obar)
  u16*   newx  = (u16*)  (w + 48240640);    //  8192x512  bf16 (dead after LN1)
  u16*   ybuf  = newx;                      //  8192x512  bf16 (aliases newx)
  u16*   x1b   = (u16*)  (w + 56629248);    //  8192x512  bf16
  // total ws usage: 65,017,856 bytes

  // --- prep ---
  transpose_f2b<<<dim3(16, 16), 256, 0, stream>>>(Wq, WqkvT,            512, 512);
  transpose_f2b<<<dim3(16, 16), 256, 0, stream>>>(Wk, WqkvT + 262144,   512, 512);
  transpose_f2b<<<dim3(16, 16), 256, 0, stream>>>(Wv, WqkvT + 524288,   512, 512);
  transpose_f2b<<<dim3(16, 16), 256, 0, stream>>>(Wo, WoT,              512, 512);
  transpose_f2b<<<dim3(64, 16), 256, 0, stream>>>(W1, W1T,              512, 2048);
  transpose_f2b<<<dim3(16, 64), 256, 0, stream>>>(W2, W2T,             2048, 512);
  concat_bias<<<6, 256, 0, stream>>>(bq, bk, bv, bqkv);
  f2b_vec<<<4096, 256, 0, stream>>>(x, xb, 1048576);

  // --- G1: QKV ---
  gemm_bt<0><<<dim3(12, 64), 256, 0, stream>>>(xb, WqkvT, bqkv, QKV, 8192, 1536, 512);
  // --- attention ---
  attn_kernel<<<8192, 256, 0, stream>>>(QKV, bqkv, obar);
  // --- G2: Wo ---
  gemm_bt<0><<<dim3(4, 64), 256, 0, stream>>>(obar, WoT, bo, newx, 8192, 512, 512);
  // --- LN1 ---
  ln_kernel<0><<<2048, 256, 0, stream>>>(x, nullptr, newx, g1, be1, x1b, nullptr);
  // --- G3: W1 + gelu ---
  gemm_bt<1><<<dim3(16, 64), 256, 0, stream>>>(x1b, W1T, b1, hbuf, 8192, 2048, 512);
  // --- G4: W2 ---
  gemm_bt<0><<<dim3(4, 64), 256, 0, stream>>>(hbuf, W2T, b2, ybuf, 8192, 512, 2048);
  // --- LN2 -> out ---
  ln_kernel<1><<<2048, 256, 0, stream>>>(nullptr, x1b, ybuf, g2, be2, nullptr, (float*)d_out);
}

// Round 2
// 167.520 us; speedup vs baseline: 1.3285x; 1.3285x over previous
//
#include <hip/hip_runtime.h>

// ---------------------------------------------------------------------------
// LocalWindowAttentionLayer on MI355X (gfx950)
// B=4 L=2048 D=512 H=8 DK=64 DF=2048 W=9
//
// Pipeline:
//  prep: transpose weights -> bf16 [N][K], concat qkv bias, x -> bf16
//  G1: QKV = xb @ WqkvT^T + bqkv          (8192 x 1536, K=512)  bf16 out
//  A : banded-Gram attention -> obar (8192 x 512) bf16
//  G2: newx = obar @ WoT^T + bo           (8192 x 512, K=512)   bf16 out
//  LN1: x1 = LN(x + newx)                 -> bf16
//  G3: h = gelu(x1 @ W1T^T + b1)          (8192 x 2048, K=512)  bf16 out
//  G4: y = h @ W2T^T + b2                 (8192 x 512, K=2048)  bf16 out
//  LN2: out = LN(x1 + y)                  -> fp32 d_out
// ---------------------------------------------------------------------------

typedef unsigned short u16;
typedef __attribute__((ext_vector_type(8))) short short8;   // 8 bf16 (4 VGPRs)
typedef __attribute__((ext_vector_type(4))) float floatx4;  // MFMA acc

#define DEV static __device__ __forceinline__

DEV float b2f(u16 u) {
  union { unsigned int i; float f; } x; x.i = ((unsigned int)u) << 16; return x.f;
}
DEV u16 f2b(float f) {  // round-to-nearest-even
  union { float f; unsigned int i; } x; x.f = f;
  unsigned int u = x.i + 0x7fffu + ((x.i >> 16) & 1u);
  return (u16)(u >> 16);
}

#define AS1 __attribute__((address_space(1)))
#define AS3 __attribute__((address_space(3)))
DEV void gload_lds16(const void* g, void* l) {
  __builtin_amdgcn_global_load_lds((const AS1 void*)g, (AS3 void*)l, 16, 0, 0);
}

// ---------------------------------------------------------------------------
// Tiled transpose: in (R x C) fp32 -> out (C x R) bf16
// ---------------------------------------------------------------------------
__global__ __launch_bounds__(256) void transpose_f2b(
    const float* __restrict__ in, u16* __restrict__ out, int R, int C) {
  __shared__ float tile[32][33];
  const int tx = threadIdx.x & 31, ty = threadIdx.x >> 5;
  const int bc = blockIdx.x * 32, br = blockIdx.y * 32;
  #pragma unroll
  for (int i = 0; i < 32; i += 8)
    tile[ty + i][tx] = in[(size_t)(br + ty + i) * C + bc + tx];
  __syncthreads();
  #pragma unroll
  for (int i = 0; i < 32; i += 8)
    out[(size_t)(bc + ty + i) * R + br + tx] = f2b(tile[tx][ty + i]);
}

__global__ __launch_bounds__(256) void concat_bias(
    const float* __restrict__ bq, const float* __restrict__ bk,
    const float* __restrict__ bv, float* __restrict__ o) {
  int i = blockIdx.x * 256 + threadIdx.x;
  if (i < 512) o[i] = bq[i];
  else if (i < 1024) o[i] = bk[i - 512];
  else if (i < 1536) o[i] = bv[i - 1024];
}

__global__ __launch_bounds__(256) void f2b_vec(
    const float* __restrict__ in, u16* __restrict__ out, int n4) {
  int i = blockIdx.x * 256 + threadIdx.x;
  if (i < n4) {
    float4 v = ((const float4*)in)[i];
    ushort4 o;
    o.x = f2b(v.x); o.y = f2b(v.y); o.z = f2b(v.z); o.w = f2b(v.w);
    ((ushort4*)out)[i] = o;
  }
}

// ---------------------------------------------------------------------------
// bf16 MFMA GEMM:  C[M][N] = A[M][K] @ BT[N][K]^T + bias ; EPI: 0=bias, 1=bias+gelu
// BM=BN=128, BK=32, 256 threads = 4 waves, each wave 64x64 (4x4 frags 16x16x32)
// ---------------------------------------------------------------------------
template<int EPI>
__global__ __launch_bounds__(256, 2) void gemm_bt(
    const u16* __restrict__ A, const u16* __restrict__ BT,
    const float* __restrict__ bias, u16* __restrict__ C,
    int M, int N, int K) {
  __shared__ __align__(16) u16 As[128 * 32];
  __shared__ __align__(16) u16 Bs[128 * 32];
  const int tid  = threadIdx.x;
  const int wave = tid >> 6, lane = tid & 63;
  const int l15 = lane & 15, l4 = lane >> 4;
  const int bm = blockIdx.y * 128, bn = blockIdx.x * 128;
  const int wm = (wave >> 1) * 64, wn = (wave & 1) * 64;

  floatx4 acc[4][4] = {};

  const int row0 = tid >> 2, kc0 = (tid & 3) * 8;
  const u16* gA = A  + (size_t)(bm + row0) * K + kc0;
  const u16* gB = BT + (size_t)(bn + row0) * K + kc0;
  u16* lA0 = As + wave * 512;
  u16* lB0 = Bs + wave * 512;
  u16* lA1 = As + 2048 + wave * 512;
  u16* lB1 = Bs + 2048 + wave * 512;

  for (int k0 = 0; k0 < K; k0 += 32) {
    gload_lds16(gA, lA0);
    gload_lds16(gB, lB0);
    gload_lds16(gA + (size_t)64 * K, lA1);
    gload_lds16(gB + (size_t)64 * K, lB1);
    gA += 32; gB += 32;
    __syncthreads();

    short8 af[4], bf[4];
    #pragma unroll
    for (int i = 0; i < 4; ++i) {
      af[i] = *(const short8*)(As + (wm + i * 16 + l15) * 32 + l4 * 8);
      bf[i] = *(const short8*)(Bs + (wn + i * 16 + l15) * 32 + l4 * 8);
    }
    #pragma unroll
    for (int i = 0; i < 4; ++i)
      #pragma unroll
      for (int j = 0; j < 4; ++j)
        acc[i][j] = __builtin_amdgcn_mfma_f32_16x16x32_bf16(af[i], bf[j], acc[i][j], 0, 0, 0);
    __syncthreads();
  }

  float bv[4];
  #pragma unroll
  for (int j = 0; j < 4; ++j) bv[j] = bias[bn + wn + j * 16 + l15];
  #pragma unroll
  for (int i = 0; i < 4; ++i) {
    #pragma unroll
    for (int r = 0; r < 4; ++r) {
      size_t row = (size_t)(bm + wm + i * 16 + l4 * 4 + r);
      u16* cp = C + row * N + (bn + wn + l15);
      #pragma unroll
      for (int j = 0; j < 4; ++j) {
        float v = acc[i][j][r] + bv[j];
        if (EPI == 1) v = 0.5f * v * (1.0f + erff(v * 0.70710678118654752f));
        cp[j * 16] = f2b(v);
      }
    }
  }
}

// ---------------------------------------------------------------------------
// Banded-Gram attention. One block per (b, 32-pos chunk, head).
//   scores[l][qw][kw] = G[l+qw-4, l+kw-4],  G[t,u]=Q[t]�K[u] (band |t-u|<=8)
//   wbar[l][kw] = (1/9) sum_qw softmax_kw(scores[l][qw][:])
//   obar[l][h*64+d] = sum_kw wbar[l][kw] * V[l+kw-4][h*64+d]
// Rows t in [l0-4, l0+36); out-of-range rows = projected-zero = bias.
// ---------------------------------------------------------------------------
#define ATL 32
#define ART (ATL + 8)   // 40 staged rows

__global__ __launch_bounds__(256) void attn_band(
    const u16* __restrict__ QKV, const float* __restrict__ bqkv,
    u16* __restrict__ obar) {
  __shared__ __align__(16) u16 S3[3][ART][72];  // Q,K,V head slice; pad 64->72 (4-bank row skew)
  __shared__ float Gb[ART][18];                 // band: j = u - t + 8 in [0,17)
  __shared__ float Sm[ART][81];                 // softmax rows [t][qw*9+kw]
  __shared__ float Wb[ATL][9];

  const int tid = threadIdx.x;
  // XCD-aware swizzle (2048 blocks % 8 == 0 -> bijective): heads sharing rows
  // and adjacent chunks co-locate on one XCD's L2.
  const int bid = ((int)blockIdx.x & 7) * 256 + ((int)blockIdx.x >> 3);
  const int h = bid & 7;
  const int chunk = (bid >> 3) & 63;
  const int b = bid >> 9;
  const int l0 = chunk * ATL;

  // --- stage Q/K/V head slices for rows [l0-4, l0+36) ---
  for (int idx = tid; idx < ART * 24; idx += 256) {
    const int ti = idx / 24, c = idx % 24;
    const int slice = c >> 3, d8 = (c & 7) * 8;
    const int col = slice * 512 + h * 64 + d8;
    const int t = l0 - 4 + ti;
    short8 v;
    if ((unsigned)t < 2048u) {
      v = *(const short8*)(QKV + ((size_t)((b << 11) | t)) * 1536 + col);
    } else {
      #pragma unroll
      for (int j = 0; j < 8; ++j) v[j] = (short)f2b(bqkv[col + j]);
    }
    *(short8*)(&S3[slice][ti][d8]) = v;
  }
  __syncthreads();

  // --- banded Gram: 680 tasks (ti, j) ---
  for (int task = tid; task < ART * 17; task += 256) {
    const int ti = task / 17, j = task % 17;
    const int ui = ti + j - 8;
    if ((unsigned)ui < (unsigned)ART) {
      float a = 0.f;
      #pragma unroll
      for (int d0 = 0; d0 < 64; d0 += 8) {
        short8 qv = *(const short8*)(&S3[0][ti][d0]);
        short8 kv = *(const short8*)(&S3[1][ui][d0]);
        #pragma unroll
        for (int jj = 0; jj < 8; ++jj) a += b2f((u16)qv[jj]) * b2f((u16)kv[jj]);
      }
      Gb[ti][j] = a * 0.125f;
    }
  }
  __syncthreads();

  // --- softmax per (ti, qw): window j in [8-qw, 16-qw], valid if li=ti-qw in chunk ---
  for (int task = tid; task < ART * 9; task += 256) {
    const int ti = task / 9, qw = task % 9;
    const int li = ti - qw;
    if ((unsigned)li < (unsigned)ATL) {
      float m = -1e30f;
      #pragma unroll
      for (int kw = 0; kw < 9; ++kw) m = fmaxf(m, Gb[ti][kw - qw + 8]);
      float e[9], s = 0.f;
      #pragma unroll
      for (int kw = 0; kw < 9; ++kw) { e[kw] = expf(Gb[ti][kw - qw + 8] - m); s += e[kw]; }
      const float inv = 1.f / s;
      #pragma unroll
      for (int kw = 0; kw < 9; ++kw) Sm[ti][qw * 9 + kw] = e[kw] * inv;
    }
  }
  __syncthreads();

  // --- column-mean over qw: wbar[li][kw] ---
  for (int task = tid; task < ATL * 9; task += 256) {
    const int li = task / 9, kw = task % 9;
    float s = 0.f;
    #pragma unroll
    for (int qw = 0; qw < 9; ++qw) s += Sm[li + qw][qw * 9 + kw];
    Wb[li][kw] = s * (1.f / 9.f);
  }
  __syncthreads();

  // --- weighted V sum: 256 tasks exactly, tid -> (li, 8-elem chunk) ---
  {
    const int li = tid >> 3, d8 = (tid & 7) * 8;
    float w[9];
    #pragma unroll
    for (int kw = 0; kw < 9; ++kw) w[kw] = Wb[li][kw];
    float a[8] = {};
    #pragma unroll
    for (int kw = 0; kw < 9; ++kw) {
      short8 vv = *(const short8*)(&S3[2][li + kw][d8]);
      #pragma unroll
      for (int jj = 0; jj < 8; ++jj) a[jj] += w[kw] * b2f((u16)vv[jj]);
    }
    short8 o;
    #pragma unroll
    for (int jj = 0; jj < 8; ++jj) o[jj] = (short)f2b(a[jj]);
    const int l = l0 + li;
    *(short8*)(obar + ((size_t)((b << 11) | l)) * 512 + h * 64 + d8) = o;
  }
}

// ---------------------------------------------------------------------------
// LayerNorm over D=512. One wave per row, 4 rows per block.
// MODE 0: v = af(f32) + bb(bf16) -> outb bf16
// MODE 1: v = ab(bf16) + bb(bf16) -> outf fp32
// ---------------------------------------------------------------------------
template<int MODE>
__global__ __launch_bounds__(256) void ln_kernel(
    const float* __restrict__ af, const u16* __restrict__ ab,
    const u16* __restrict__ bb,
    const float* __restrict__ g, const float* __restrict__ be,
    u16* __restrict__ outb, float* __restrict__ outf) {
  const int wave = threadIdx.x >> 6, lane = threadIdx.x & 63;
  const size_t row = (size_t)blockIdx.x * 4 + wave;
  const size_t base = row * 512 + lane * 8;
  const int gi = lane * 8;
  float v[8];
  short8 b8 = *(const short8*)(bb + base);
  if (MODE == 0) {
    float4 a0 = *(const float4*)(af + base);
    float4 a1 = *(const float4*)(af + base + 4);
    v[0] = a0.x; v[1] = a0.y; v[2] = a0.z; v[3] = a0.w;
    v[4] = a1.x; v[5] = a1.y; v[6] = a1.z; v[7] = a1.w;
  } else {
    short8 a8 = *(const short8*)(ab + base);
    #pragma unroll
    for (int j = 0; j < 8; ++j) v[j] = b2f((u16)a8[j]);
  }
  #pragma unroll
  for (int j = 0; j < 8; ++j) v[j] += b2f((u16)b8[j]);

  float s = 0.f;
  #pragma unroll
  for (int j = 0; j < 8; ++j) s += v[j];
  #pragma unroll
  for (int off = 32; off >= 1; off >>= 1) s += __shfl_xor(s, off, 64);
  const float mean = s * (1.f / 512.f);
  float sq = 0.f;
  #pragma unroll
  for (int j = 0; j < 8; ++j) { float d = v[j] - mean; sq += d * d; }
  #pragma unroll
  for (int off = 32; off >= 1; off >>= 1) sq += __shfl_xor(sq, off, 64);
  const float rs = rsqrtf(sq * (1.f / 512.f) + 1e-5f);

  if (MODE == 0) {
    short8 o;
    #pragma unroll
    for (int j = 0; j < 8; ++j)
      o[j] = (short)f2b((v[j] - mean) * rs * g[gi + j] + be[gi + j]);
    *(short8*)(outb + base) = o;
  } else {
    float4 o0, o1;
    o0.x = (v[0] - mean) * rs * g[gi + 0] + be[gi + 0];
    o0.y = (v[1] - mean) * rs * g[gi + 1] + be[gi + 1];
    o0.z = (v[2] - mean) * rs * g[gi + 2] + be[gi + 2];
    o0.w = (v[3] - mean) * rs * g[gi + 3] + be[gi + 3];
    o1.x = (v[4] - mean) * rs * g[gi + 4] + be[gi + 4];
    o1.y = (v[5] - mean) * rs * g[gi + 5] + be[gi + 5];
    o1.z = (v[6] - mean) * rs * g[gi + 6] + be[gi + 6];
    o1.w = (v[7] - mean) * rs * g[gi + 7] + be[gi + 7];
    *(float4*)(outf + base) = o0;
    *(float4*)(outf + base + 4) = o1;
  }
}

// ---------------------------------------------------------------------------
extern "C" void kernel_launch(void* const* d_in, const int* in_sizes, int n_in,
                              void* d_out, int out_size, void* d_ws, size_t ws_size,
                              hipStream_t stream) {
  const float* x   = (const float*)d_in[0];
  const float* Wq  = (const float*)d_in[1];
  const float* bq  = (const float*)d_in[2];
  const float* Wk  = (const float*)d_in[3];
  const float* bk  = (const float*)d_in[4];
  const float* Wv  = (const float*)d_in[5];
  const float* bv  = (const float*)d_in[6];
  const float* Wo  = (const float*)d_in[7];
  const float* bo  = (const float*)d_in[8];
  const float* W1  = (const float*)d_in[9];
  const float* b1  = (const float*)d_in[10];
  const float* W2  = (const float*)d_in[11];
  const float* b2  = (const float*)d_in[12];
  const float* g1  = (const float*)d_in[13];
  const float* be1 = (const float*)d_in[14];
  const float* g2  = (const float*)d_in[15];
  const float* be2 = (const float*)d_in[16];

  char* w = (char*)d_ws;
  u16*   xb    = (u16*)  (w + 0);           //  8 MB
  u16*   WqkvT = (u16*)  (w + 8388608);     //  1536x512 bf16
  u16*   WoT   = (u16*)  (w + 9961472);     //  512x512
  u16*   W1T   = (u16*)  (w + 10485760);    //  2048x512
  u16*   W2T   = (u16*)  (w + 12582912);    //  512x2048
  float* bqkv  = (float*)(w + 14680064);    //  1536 f32
  u16*   QKV   = (u16*)  (w + 14686208);    //  8192x1536 bf16 (dead after attn)
  u16*   obar  = (u16*)  (w + 39852032);    //  8192x512  bf16 (dead after G2)
  u16*   hbuf  = QKV;                       //  8192x2048 bf16 (aliases QKV+obar)
  u16*   newx  = (u16*)  (w + 48240640);    //  8192x512  bf16 (dead after LN1)
  u16*   ybuf  = newx;                      //  8192x512  bf16 (aliases newx)
  u16*   x1b   = (u16*)  (w + 56629248);    //  8192x512  bf16

  // --- prep ---
  transpose_f2b<<<dim3(16, 16), 256, 0, stream>>>(Wq, WqkvT,            512, 512);
  transpose_f2b<<<dim3(16, 16), 256, 0, stream>>>(Wk, WqkvT + 262144,   512, 512);
  transpose_f2b<<<dim3(16, 16), 256, 0, stream>>>(Wv, WqkvT + 524288,   512, 512);
  transpose_f2b<<<dim3(16, 16), 256, 0, stream>>>(Wo, WoT,              512, 512);
  transpose_f2b<<<dim3(64, 16), 256, 0, stream>>>(W1, W1T,              512, 2048);
  transpose_f2b<<<dim3(16, 64), 256, 0, stream>>>(W2, W2T,             2048, 512);
  concat_bias<<<6, 256, 0, stream>>>(bq, bk, bv, bqkv);
  f2b_vec<<<4096, 256, 0, stream>>>(x, xb, 1048576);

  // --- G1: QKV ---
  gemm_bt<0><<<dim3(12, 64), 256, 0, stream>>>(xb, WqkvT, bqkv, QKV, 8192, 1536, 512);
  // --- attention (banded Gram) ---
  attn_band<<<2048, 256, 0, stream>>>(QKV, bqkv, obar);
  // --- G2: Wo ---
  gemm_bt<0><<<dim3(4, 64), 256, 0, stream>>>(obar, WoT, bo, newx, 8192, 512, 512);
  // --- LN1 ---
  ln_kernel<0><<<2048, 256, 0, stream>>>(x, nullptr, newx, g1, be1, x1b, nullptr);
  // --- G3: W1 + gelu ---
  gemm_bt<1><<<dim3(16, 64), 256, 0, stream>>>(x1b, W1T, b1, hbuf, 8192, 2048, 512);
  // --- G4: W2 ---
  gemm_bt<0><<<dim3(4, 64), 256, 0, stream>>>(hbuf, W2T, b2, ybuf, 8192, 512, 2048);
  // --- LN2 -> out ---
  ln_kernel<1><<<2048, 256, 0, stream>>>(nullptr, x1b, ybuf, g2, be2, nullptr, (float*)d_out);
}

// Round 3
// 167.249 us; speedup vs baseline: 1.3307x; 1.0016x over previous
//
#include <hip/hip_runtime.h>

// ---------------------------------------------------------------------------
// LocalWindowAttentionLayer on MI355X (gfx950)
// B=4 L=2048 D=512 H=8 DK=64 DF=2048 W=9
//
// Pipeline (G2 folded into G1 via Wvo = Wv@Wo):
//  prep: fused transpose weights -> bf16 [N][K]; bias prep (bq,bk,bvo=bv@Wo,0)
//  W  : WvoT = (Wv@Wo)^T  (tiny bf16 GEMM)
//  G1 : QKV'' = xb @ [Wq;Wk;Wvo]^T + [bq;bk;bvo]   (8192 x 1536, K=512)
//  A  : banded-Gram attention -> newx = sum_kw wbar*V'' + bo  (8192 x 512)
//  LN1: x1 = LN(x + newx)
//  G3 : h = gelu(x1 @ W1T^T + b1)       (8192 x 2048, K=512)
//  G4 : y = h @ W2T^T + b2              (8192 x 512,  K=2048)
//  LN2: out = LN(x1 + y) -> fp32
// GEMM: 128x128 tile, BK=32, 2-phase double-buffered LDS, raw s_barrier +
//       vmcnt(0) drain once per iter (stage(t+1) overlaps compute(t)).
// ---------------------------------------------------------------------------

typedef unsigned short u16;
typedef __attribute__((ext_vector_type(8))) short short8;   // 8 bf16
typedef __attribute__((ext_vector_type(4))) float floatx4;  // MFMA acc

#define DEV static __device__ __forceinline__

DEV float b2f(u16 u) {
  union { unsigned int i; float f; } x; x.i = ((unsigned int)u) << 16; return x.f;
}
DEV u16 f2b(float f) {  // round-to-nearest-even
  union { float f; unsigned int i; } x; x.f = f;
  unsigned int u = x.i + 0x7fffu + ((x.i >> 16) & 1u);
  return (u16)(u >> 16);
}

#define AS1 __attribute__((address_space(1)))
#define AS3 __attribute__((address_space(3)))
DEV void gload_lds16(const void* g, void* l) {
  __builtin_amdgcn_global_load_lds((const AS1 void*)g, (AS3 void*)l, 16, 0, 0);
}

// ---------------------------------------------------------------------------
// Fused weight prep: transposes (fp32 RxC -> bf16 CxR) for Wq,Wk,Wo,W1,W2
// plus straight f2b copy of Wv. One launch.
// blocks: [0,256) Wq | [256,512) Wk | [512,768) Wo | [768,1792) W1
//         [1792,2816) W2 | [2816,3072) Wv copy
// ---------------------------------------------------------------------------
__global__ __launch_bounds__(256) void prep_weights(
    const float* __restrict__ Wq, const float* __restrict__ Wk,
    const float* __restrict__ Wo, const float* __restrict__ W1,
    const float* __restrict__ W2, const float* __restrict__ Wv,
    u16* __restrict__ WqkvT, u16* __restrict__ WoT,
    u16* __restrict__ W1T, u16* __restrict__ W2T, u16* __restrict__ Wvb) {
  const int bid = blockIdx.x;
  if (bid >= 2816) {  // Wv f2b copy (512x512)
    const int i = (bid - 2816) * 256 + threadIdx.x;
    float4 v = ((const float4*)Wv)[i];
    ushort4 o;
    o.x = f2b(v.x); o.y = f2b(v.y); o.z = f2b(v.z); o.w = f2b(v.w);
    ((ushort4*)Wvb)[i] = o;
    return;
  }
  const float* in; u16* out; int R, C, t;
  if (bid < 256)       { in = Wq; out = WqkvT;          R = 512;  C = 512;  t = bid; }
  else if (bid < 512)  { in = Wk; out = WqkvT + 262144; R = 512;  C = 512;  t = bid - 256; }
  else if (bid < 768)  { in = Wo; out = WoT;            R = 512;  C = 512;  t = bid - 512; }
  else if (bid < 1792) { in = W1; out = W1T;            R = 512;  C = 2048; t = bid - 768; }
  else                 { in = W2; out = W2T;            R = 2048; C = 512;  t = bid - 1792; }
  const int tpr = C >> 5;  // tiles per row-band
  const int bc = (t % tpr) * 32, br = (t / tpr) * 32;
  __shared__ float tile[32][33];
  const int tx = threadIdx.x & 31, ty = threadIdx.x >> 5;
  #pragma unroll
  for (int i = 0; i < 32; i += 8)
    tile[ty + i][tx] = in[(size_t)(br + ty + i) * C + bc + tx];
  __syncthreads();
  #pragma unroll
  for (int i = 0; i < 32; i += 8)
    out[(size_t)(bc + ty + i) * R + br + tx] = f2b(tile[tx][ty + i]);
}

// bqkv[0:512)=bq, [512:1024)=bk, [1024:1536)=bvo=bv@Wo, [1536:2048)=0
__global__ __launch_bounds__(256) void bias_prep(
    const float* __restrict__ bq, const float* __restrict__ bk,
    const float* __restrict__ bv, const float* __restrict__ Wo,
    float* __restrict__ o) {
  const int i = blockIdx.x * 256 + threadIdx.x;
  if (i < 512) o[i] = bq[i];
  else if (i < 1024) o[i] = bk[i - 512];
  else if (i < 1536) {
    const int c = i - 1024;
    float s = 0.f;
    for (int j = 0; j < 512; ++j) s += bv[j] * Wo[(size_t)j * 512 + c];
    o[i] = s;
  } else if (i < 2048) o[i] = 0.f;
}

__global__ __launch_bounds__(256) void f2b_vec(
    const float* __restrict__ in, u16* __restrict__ out, int n4) {
  int i = blockIdx.x * 256 + threadIdx.x;
  if (i < n4) {
    float4 v = ((const float4*)in)[i];
    ushort4 o;
    o.x = f2b(v.x); o.y = f2b(v.y); o.z = f2b(v.z); o.w = f2b(v.w);
    ((ushort4*)out)[i] = o;
  }
}

// ---------------------------------------------------------------------------
// bf16 MFMA GEMM: C[M][N] = A[M][K] @ BT[N][K]^T + bias ; EPI: 0=bias, 1=bias+gelu
// BM=BN=128, BK=32, 256 thr = 4 waves (2x2), wave 64x64 = 4x4 frags 16x16x32.
// 2-phase dbuf: stage(t+1) issued before compute(t); one raw barrier + vmcnt(0)
// drain per iteration.
// ---------------------------------------------------------------------------
template<int EPI>
__global__ __launch_bounds__(256, 2) void gemm_bt(
    const u16* __restrict__ A, const u16* __restrict__ BT,
    const float* __restrict__ bias, u16* __restrict__ C,
    int M, int N, int K) {
  __shared__ __align__(16) u16 As[2][128 * 32];
  __shared__ __align__(16) u16 Bs[2][128 * 32];
  const int tid  = threadIdx.x;
  const int wave = tid >> 6, lane = tid & 63;
  const int l15 = lane & 15, l4 = lane >> 4;
  const int bm = blockIdx.y * 128, bn = blockIdx.x * 128;
  const int wm = (wave >> 1) * 64, wn = (wave & 1) * 64;

  floatx4 acc[4][4] = {};

  // staging: thread -> chunk (row0 = tid>>2 in [0,64), 16B k-chunk kc0)
  const int row0 = tid >> 2, kc0 = (tid & 3) * 8;
  const u16* gA = A  + (size_t)(bm + row0) * K + kc0;
  const u16* gB = BT + (size_t)(bn + row0) * K + kc0;
  const int lofs = wave * 512;  // wave-uniform LDS chunk base (elements)

  auto stage = [&](int t, int buf) {
    const u16* a = gA + t * 32;
    const u16* b = gB + t * 32;
    gload_lds16(a,                  &As[buf][lofs]);
    gload_lds16(b,                  &Bs[buf][lofs]);
    gload_lds16(a + (size_t)64 * K, &As[buf][lofs + 2048]);
    gload_lds16(b + (size_t)64 * K, &Bs[buf][lofs + 2048]);
  };

  const int nt = K >> 5;
  stage(0, 0);
  asm volatile("s_waitcnt vmcnt(0)" ::: "memory");
  __builtin_amdgcn_s_barrier();

  for (int t = 0; t < nt; ++t) {
    const int cur = t & 1;
    if (t + 1 < nt) stage(t + 1, cur ^ 1);

    short8 af[4], bf4[4];
    #pragma unroll
    for (int i = 0; i < 4; ++i) {
      af[i]  = *(const short8*)(&As[cur][(wm + i * 16 + l15) * 32 + l4 * 8]);
      bf4[i] = *(const short8*)(&Bs[cur][(wn + i * 16 + l15) * 32 + l4 * 8]);
    }
    #pragma unroll
    for (int i = 0; i < 4; ++i)
      #pragma unroll
      for (int j = 0; j < 4; ++j)
        acc[i][j] = __builtin_amdgcn_mfma_f32_16x16x32_bf16(af[i], bf4[j], acc[i][j], 0, 0, 0);

    // next tile must be resident before anyone reads it; current buffer's
    // reads are already consumed (MFMA dependency) before this barrier.
    asm volatile("s_waitcnt vmcnt(0)" ::: "memory");
    __builtin_amdgcn_s_barrier();
  }

  float bv[4];
  #pragma unroll
  for (int j = 0; j < 4; ++j) bv[j] = bias[bn + wn + j * 16 + l15];
  #pragma unroll
  for (int i = 0; i < 4; ++i) {
    #pragma unroll
    for (int r = 0; r < 4; ++r) {
      size_t row = (size_t)(bm + wm + i * 16 + l4 * 4 + r);
      u16* cp = C + row * N + (bn + wn + l15);
      #pragma unroll
      for (int j = 0; j < 4; ++j) {
        float v = acc[i][j][r] + bv[j];
        if (EPI == 1) v = 0.5f * v * (1.0f + erff(v * 0.70710678118654752f));
        cp[j * 16] = f2b(v);
      }
    }
  }
}

// ---------------------------------------------------------------------------
// Banded-Gram attention. One block per (b, 32-pos chunk, head).
// V here is V'' = win @ Wvo + bvo, so output is newx directly (+bo).
// ---------------------------------------------------------------------------
#define ATL 32
#define ART (ATL + 8)   // 40 staged rows

__global__ __launch_bounds__(256) void attn_band(
    const u16* __restrict__ QKV, const float* __restrict__ bqkv,
    const float* __restrict__ bo, u16* __restrict__ newx) {
  __shared__ __align__(16) u16 S3[3][ART][72];
  __shared__ float Gb[ART][18];
  __shared__ float Sm[ART][81];
  __shared__ float Wb[ATL][9];

  const int tid = threadIdx.x;
  const int bid = ((int)blockIdx.x & 7) * 256 + ((int)blockIdx.x >> 3);
  const int h = bid & 7;
  const int chunk = (bid >> 3) & 63;
  const int b = bid >> 9;
  const int l0 = chunk * ATL;

  for (int idx = tid; idx < ART * 24; idx += 256) {
    const int ti = idx / 24, c = idx % 24;
    const int slice = c >> 3, d8 = (c & 7) * 8;
    const int col = slice * 512 + h * 64 + d8;
    const int t = l0 - 4 + ti;
    short8 v;
    if ((unsigned)t < 2048u) {
      v = *(const short8*)(QKV + ((size_t)((b << 11) | t)) * 1536 + col);
    } else {
      #pragma unroll
      for (int j = 0; j < 8; ++j) v[j] = (short)f2b(bqkv[col + j]);
    }
    *(short8*)(&S3[slice][ti][d8]) = v;
  }
  __syncthreads();

  for (int task = tid; task < ART * 17; task += 256) {
    const int ti = task / 17, j = task % 17;
    const int ui = ti + j - 8;
    if ((unsigned)ui < (unsigned)ART) {
      float a = 0.f;
      #pragma unroll
      for (int d0 = 0; d0 < 64; d0 += 8) {
        short8 qv = *(const short8*)(&S3[0][ti][d0]);
        short8 kv = *(const short8*)(&S3[1][ui][d0]);
        #pragma unroll
        for (int jj = 0; jj < 8; ++jj) a += b2f((u16)qv[jj]) * b2f((u16)kv[jj]);
      }
      Gb[ti][j] = a * 0.125f;
    }
  }
  __syncthreads();

  for (int task = tid; task < ART * 9; task += 256) {
    const int ti = task / 9, qw = task % 9;
    const int li = ti - qw;
    if ((unsigned)li < (unsigned)ATL) {
      float m = -1e30f;
      #pragma unroll
      for (int kw = 0; kw < 9; ++kw) m = fmaxf(m, Gb[ti][kw - qw + 8]);
      float e[9], s = 0.f;
      #pragma unroll
      for (int kw = 0; kw < 9; ++kw) { e[kw] = expf(Gb[ti][kw - qw + 8] - m); s += e[kw]; }
      const float inv = 1.f / s;
      #pragma unroll
      for (int kw = 0; kw < 9; ++kw) Sm[ti][qw * 9 + kw] = e[kw] * inv;
    }
  }
  __syncthreads();

  for (int task = tid; task < ATL * 9; task += 256) {
    const int li = task / 9, kw = task % 9;
    float s = 0.f;
    #pragma unroll
    for (int qw = 0; qw < 9; ++qw) s += Sm[li + qw][qw * 9 + kw];
    Wb[li][kw] = s * (1.f / 9.f);
  }
  __syncthreads();

  {
    const int li = tid >> 3, d8 = (tid & 7) * 8;
    float w[9];
    #pragma unroll
    for (int kw = 0; kw < 9; ++kw) w[kw] = Wb[li][kw];
    float a[8] = {};
    #pragma unroll
    for (int kw = 0; kw < 9; ++kw) {
      short8 vv = *(const short8*)(&S3[2][li + kw][d8]);
      #pragma unroll
      for (int jj = 0; jj < 8; ++jj) a[jj] += w[kw] * b2f((u16)vv[jj]);
    }
    short8 o;
    #pragma unroll
    for (int jj = 0; jj < 8; ++jj) o[jj] = (short)f2b(a[jj] + bo[h * 64 + d8 + jj]);
    const int l = l0 + li;
    *(short8*)(newx + ((size_t)((b << 11) | l)) * 512 + h * 64 + d8) = o;
  }
}

// ---------------------------------------------------------------------------
// LayerNorm over D=512. One wave per row, 4 rows per block.
// MODE 0: v = af(f32) + bb(bf16) -> outb bf16
// MODE 1: v = ab(bf16) + bb(bf16) -> outf fp32
// ---------------------------------------------------------------------------
template<int MODE>
__global__ __launch_bounds__(256) void ln_kernel(
    const float* __restrict__ af, const u16* __restrict__ ab,
    const u16* __restrict__ bb,
    const float* __restrict__ g, const float* __restrict__ be,
    u16* __restrict__ outb, float* __restrict__ outf) {
  const int wave = threadIdx.x >> 6, lane = threadIdx.x & 63;
  const size_t row = (size_t)blockIdx.x * 4 + wave;
  const size_t base = row * 512 + lane * 8;
  const int gi = lane * 8;
  float v[8];
  short8 b8 = *(const short8*)(bb + base);
  if (MODE == 0) {
    float4 a0 = *(const float4*)(af + base);
    float4 a1 = *(const float4*)(af + base + 4);
    v[0] = a0.x; v[1] = a0.y; v[2] = a0.z; v[3] = a0.w;
    v[4] = a1.x; v[5] = a1.y; v[6] = a1.z; v[7] = a1.w;
  } else {
    short8 a8 = *(const short8*)(ab + base);
    #pragma unroll
    for (int j = 0; j < 8; ++j) v[j] = b2f((u16)a8[j]);
  }
  #pragma unroll
  for (int j = 0; j < 8; ++j) v[j] += b2f((u16)b8[j]);

  float s = 0.f;
  #pragma unroll
  for (int j = 0; j < 8; ++j) s += v[j];
  #pragma unroll
  for (int off = 32; off >= 1; off >>= 1) s += __shfl_xor(s, off, 64);
  const float mean = s * (1.f / 512.f);
  float sq = 0.f;
  #pragma unroll
  for (int j = 0; j < 8; ++j) { float d = v[j] - mean; sq += d * d; }
  #pragma unroll
  for (int off = 32; off >= 1; off >>= 1) sq += __shfl_xor(sq, off, 64);
  const float rs = rsqrtf(sq * (1.f / 512.f) + 1e-5f);

  if (MODE == 0) {
    short8 o;
    #pragma unroll
    for (int j = 0; j < 8; ++j)
      o[j] = (short)f2b((v[j] - mean) * rs * g[gi + j] + be[gi + j]);
    *(short8*)(outb + base) = o;
  } else {
    float4 o0, o1;
    o0.x = (v[0] - mean) * rs * g[gi + 0] + be[gi + 0];
    o0.y = (v[1] - mean) * rs * g[gi + 1] + be[gi + 1];
    o0.z = (v[2] - mean) * rs * g[gi + 2] + be[gi + 2];
    o0.w = (v[3] - mean) * rs * g[gi + 3] + be[gi + 3];
    o1.x = (v[4] - mean) * rs * g[gi + 4] + be[gi + 4];
    o1.y = (v[5] - mean) * rs * g[gi + 5] + be[gi + 5];
    o1.z = (v[6] - mean) * rs * g[gi + 6] + be[gi + 6];
    o1.w = (v[7] - mean) * rs * g[gi + 7] + be[gi + 7];
    *(float4*)(outf + base) = o0;
    *(float4*)(outf + base + 4) = o1;
  }
}

// ---------------------------------------------------------------------------
extern "C" void kernel_launch(void* const* d_in, const int* in_sizes, int n_in,
                              void* d_out, int out_size, void* d_ws, size_t ws_size,
                              hipStream_t stream) {
  const float* x   = (const float*)d_in[0];
  const float* Wq  = (const float*)d_in[1];
  const float* bq  = (const float*)d_in[2];
  const float* Wk  = (const float*)d_in[3];
  const float* bk  = (const float*)d_in[4];
  const float* Wv  = (const float*)d_in[5];
  const float* bv  = (const float*)d_in[6];
  const float* Wo  = (const float*)d_in[7];
  const float* bo  = (const float*)d_in[8];
  const float* W1  = (const float*)d_in[9];
  const float* b1  = (const float*)d_in[10];
  const float* W2  = (const float*)d_in[11];
  const float* b2  = (const float*)d_in[12];
  const float* g1  = (const float*)d_in[13];
  const float* be1 = (const float*)d_in[14];
  const float* g2  = (const float*)d_in[15];
  const float* be2 = (const float*)d_in[16];

  char* w = (char*)d_ws;
  u16*   xb    = (u16*)  (w + 0);           // 8 MB
  u16*   WqkvT = (u16*)  (w + 8388608);     // [1536][512] bf16 (q,k,vo)
  u16*   WoT   = (u16*)  (w + 9961472);     // [512][512]
  u16*   W1T   = (u16*)  (w + 10485760);    // [2048][512]
  u16*   W2T   = (u16*)  (w + 12582912);    // [512][2048]
  float* bqkv  = (float*)(w + 14680064);    // 2048 f32 (bq,bk,bvo,zeros)
  u16*   Wvb   = (u16*)  (w + 14688256);    // [512][512] bf16 row-major Wv
  u16*   QKV   = (u16*)  (w + 15212544);    // 8192x1536 bf16 (dead after attn)
  u16*   hbuf  = QKV;                       // 8192x2048 bf16 (aliases QKV)
  u16*   newx  = (u16*)  (w + 48766976);    // 8192x512 bf16 (dead after LN1)
  u16*   ybuf  = newx;                      // 8192x512 bf16 (aliases newx)
  u16*   x1b   = (u16*)  (w + 57155584);    // 8192x512 bf16
  u16*   WvoT  = WqkvT + 524288;            // V region of WqkvT = (Wv@Wo)^T

  // --- prep ---
  prep_weights<<<3072, 256, 0, stream>>>(Wq, Wk, Wo, W1, W2, Wv,
                                         WqkvT, WoT, W1T, W2T, Wvb);
  bias_prep<<<8, 256, 0, stream>>>(bq, bk, bv, Wo, bqkv);
  f2b_vec<<<4096, 256, 0, stream>>>(x, xb, 1048576);
  // --- WvoT = (Wv@Wo)^T : C[m][n] = sum_j WoT[m][j]*Wvb[n][j] = Wvo[n][m] ---
  gemm_bt<0><<<dim3(4, 4), 256, 0, stream>>>(WoT, Wvb, bqkv + 1536, WvoT, 512, 512, 512);
  // --- G1: QKV'' ---
  gemm_bt<0><<<dim3(12, 64), 256, 0, stream>>>(xb, WqkvT, bqkv, QKV, 8192, 1536, 512);
  // --- attention (banded Gram) -> newx ---
  attn_band<<<2048, 256, 0, stream>>>(QKV, bqkv, bo, newx);
  // --- LN1 ---
  ln_kernel<0><<<2048, 256, 0, stream>>>(x, nullptr, newx, g1, be1, x1b, nullptr);
  // --- G3: W1 + gelu ---
  gemm_bt<1><<<dim3(16, 64), 256, 0, stream>>>(x1b, W1T, b1, hbuf, 8192, 2048, 512);
  // --- G4: W2 ---
  gemm_bt<0><<<dim3(4, 64), 256, 0, stream>>>(hbuf, W2T, b2, ybuf, 8192, 512, 2048);
  // --- LN2 -> out ---
  ln_kernel<1><<<2048, 256, 0, stream>>>(nullptr, x1b, ybuf, g2, be2, nullptr, (float*)d_out);
}